// Round 3
// baseline (866.073 us; speedup 1.0000x reference)
//
#include <hip/hip_runtime.h>

#define RES 1024
#define SEQ 512

typedef _Float16 f16;
typedef _Float16 half8 __attribute__((ext_vector_type(8)));
typedef float f32x4 __attribute__((ext_vector_type(4)));
typedef float f32x2 __attribute__((ext_vector_type(2), aligned(4)));
typedef unsigned int uint4v __attribute__((ext_vector_type(4)));

// LDS partial-sum layout [w8][n][r][c], round-17: row-stride 35 + per-kq column
// rotation delta(kq) = 12-4*kq.  Proof of exact 2-way (free) on BOTH sides:
//   writes (instr = fixed n,j; lanes kq,col): bank = col + 140*kq + 12-4*kq
//     = col + 8*kq (mod 32)  -> {0,8,16,24} spacing -> uniform 2-way.
//   reads  (instr = fixed w8; lanes n_e,r,c0): 16*35 = 560 = 16 (mod 32), so
//     bank = n_e*16 + 3*r + c0 + const; per half-wave (r fixed) the 32 lanes
//     cover 16 banks x2; the other half (r+1) is shifted by 3 (odd) onto the
//     complementary half -> uniform 2-way.  delta is wave-uniform on reads
//     (all 64 lanes share r>>2), so it is a pure constant shift there.
// Row content uses <=28 of 35 slots -> no cross-row aliasing.
#define PST 35
#define PIDX(w8, n, rr, cc) ((((w8) * 4 + (n)) * 16 + (rr)) * PST + (cc))

// Workspace layout (memset 0 each launch):
//   [0   , 512K) : PRIMARY H buffer 0   (plain write-back stores -> local XCD L2)
//   [512K, 1M  ) : PRIMARY H buffer 1
//   [1M  , 1.5M) : MIRROR  H buffer 0   (write-through agent stores; ONLY used
//   [1.5M, 2M  ) : MIRROR  H buffer 1    by groups that fail the placement check)
//   [2M  , 2M+1K): xcdmap, uint[256]
//
// Grid: 256 wgs x 512 threads. wg -> (group g, slice w):
//   g = (bx&7)*2 + ((bx>>3)&1), w = bx>>4   (a group's 16 wgs share bx mod 16)
// Group g owns batch rows [g*16,g*16+16); wg w owns reservoir cols [w*64,w*64+64).
// Wave k consumes K-range [k*128,(k+1)*128) -> producers {2k,2k+1}.
//
// Round-17 = round-16 (863us; raw barrier-2 kept — neutral but harmless) with
// TWO independent, counter-attributable changes:
//  (a) LDS layout PST=35 + delta(kq): eliminates the deterministic 512
//      conflict-cycles/wg-step (SQ_LDS_BANK_CONFLICT was exactly 2^26).
//  (b) retry pacing: s_sleep 2 (~128cy) at the top of the retry loop ONLY.
//      Laggard waves (the critical path) hit on attempt 1 and never sleep;
//      ahead-waiting waves pace their polls, cutting redundant 4KB re-fetch
//      traffic through the XCD L2 (~1MB/step/XCD irreducible; retries
//      multiply it and add the queueing jitter the 16-wg lockstep amplifies).
//      r15's lesson respected: no serial hops added — the successful poll
//      still IS the data.

__device__ __forceinline__ float fast_tanh(float v) {
  float vc = fminf(15.0f, fmaxf(-15.0f, v));
  float e = __expf(2.0f * vc);
  return (e - 1.0f) * __builtin_amdgcn_rcpf(e + 1.0f);
}

#define FULL_LOAD(ptr)                                                  \
  asm volatile(                                                         \
      "global_load_dwordx4 %0, %4, off sc0 sc1\n\t"                     \
      "global_load_dwordx4 %1, %4, off offset:64 sc0 sc1\n\t"           \
      "global_load_dwordx4 %2, %4, off offset:128 sc0 sc1\n\t"          \
      "global_load_dwordx4 %3, %4, off offset:192 sc0 sc1\n\t"          \
      "s_waitcnt vmcnt(0)"                                              \
      : "=&v"(A0), "=&v"(A1), "=&v"(A2), "=&v"(A3) : "v"(ptr) : "memory")

__device__ __forceinline__ bool tags_ok(half8 A0, half8 A1, half8 A2, half8 A3,
                                        unsigned int tagr) {
  const uint4v b0 = __builtin_bit_cast(uint4v, A0);
  const uint4v b1 = __builtin_bit_cast(uint4v, A1);
  const uint4v b2 = __builtin_bit_cast(uint4v, A2);
  const uint4v b3 = __builtin_bit_cast(uint4v, A3);
  unsigned int d =
      (b0.x ^ tagr) | (b0.y ^ tagr) | (b0.z ^ tagr) | (b0.w ^ tagr) |
      (b1.x ^ tagr) | (b1.y ^ tagr) | (b1.z ^ tagr) | (b1.w ^ tagr) |
      (b2.x ^ tagr) | (b2.y ^ tagr) | (b2.z ^ tagr) | (b2.w ^ tagr) |
      (b3.x ^ tagr) | (b3.y ^ tagr) | (b3.z ^ tagr) | (b3.w ^ tagr);
  return ((d & 1u) == 0u);
}

__global__ __launch_bounds__(512, 2) void res_recur_kernel(
    const float* __restrict__ x,      // [256][512]
    const float* __restrict__ W_in,   // [1024]
    const float* __restrict__ W_res,  // [1024][1024]
    f16* __restrict__ hp0,            // primary buffers
    f16* __restrict__ hp1,
    f16* __restrict__ hm0,            // mirror buffers (fallback groups only)
    f16* __restrict__ hm1,
    unsigned int* __restrict__ xcdmap)
{
  // 20608 floats = 82,432 B: content tops out at index 17900; the tail is LDS
  // ballast (single statically-sized object — cannot be stripped) keeping the
  // block > 80 KB so only ONE wg fits per CU (the round-14 lever).
  __shared__ float P[20608];
  __shared__ unsigned char xmap_s[256];
  __shared__ int l2mode_s;

  const int tid  = threadIdx.x;
  const int wave = tid >> 6;
  const int lane = tid & 63;
  const int col  = lane & 15;
  const int kq   = (lane >> 4) & 3;

  const int bx = blockIdx.x;
  const int g  = (bx & 7) * 2 + ((bx >> 3) & 1);
  const int w  = bx >> 4;

  // ---- publish my XCC id (write-through agent store -> globally visible)
  unsigned int myxcc;
  asm volatile("s_getreg_b32 %0, hwreg(HW_REG_XCC_ID, 0, 8)" : "=s"(myxcc));
  if (tid == 0)
    __hip_atomic_store(&xcdmap[bx], (myxcc & 0xffu) + 1u, __ATOMIC_RELAXED,
                       __HIP_MEMORY_SCOPE_AGENT);

  // ---- W_res fragments (MFMA B operand), register-resident for the whole run.
  // Wf[n][ks] elem j = W_res[w*64+n*16+col][ wave*128 + ks*32 + kq*8 + j ]
  half8 Wf[4][4];
#pragma unroll
  for (int n = 0; n < 4; ++n) {
    const float* Wr = W_res + (size_t)(w * 64 + n * 16 + col) * RES + wave * 128 + kq * 8;
#pragma unroll
    for (int ks = 0; ks < 4; ++ks) {
      f32x4 lo = *(const f32x4*)(Wr + ks * 32);
      f32x4 hi = *(const f32x4*)(Wr + ks * 32 + 4);
      half8 f;
#pragma unroll
      for (int j = 0; j < 4; ++j) { f[j] = (f16)lo[j]; f[j + 4] = (f16)hi[j]; }
      Wf[n][ks] = f;
    }
  }

  // ---- gather all 256 XCC ids (coherent sc0 sc1 loads; 256 wgs on 256 CUs are
  // trivially co-resident at 1 wg/CU, so this terminates)
  if (tid < 256) {
    const unsigned int* ap = xcdmap + tid;
    unsigned int v;
    do {
      asm volatile("global_load_dword %0, %1, off sc0 sc1\n\t"
                   "s_waitcnt vmcnt(0)"
                   : "=&v"(v) : "v"(ap) : "memory");
    } while (v == 0u);
    xmap_s[tid] = (unsigned char)v;
  }
  __syncthreads();
  if (tid == 0) {
    const int base = (g >> 1) + 8 * (g & 1);   // bx of this group's w=0 member
    const unsigned char ref = xmap_s[base];
    int ok = 1, cnt = 0;
    for (int i = 0; i < 256; ++i) cnt += (xmap_s[i] == ref) ? 1 : 0;
    for (int k = 0; k < 16; ++k) ok &= (xmap_s[base + 16 * k] == ref) ? 1 : 0;
    l2mode_s = (ok && cnt <= 64) ? 1 : 0;
  }
  __syncthreads();
  const bool l2mode = (l2mode_s != 0);   // group-uniform by construction

  // ---- epilogue assignment: thread t -> (batch-row r, col pair) of the 16x64 tile
  const int r   = tid >> 5;            // 0..15
  const int cp  = tid & 31;            // col pair
  const int n_e = cp >> 3;             // n-tile 0..3
  const int c0  = (cp & 7) * 2;        // even col within tile
  const int rd_off = 12 - 4 * (r >> 2);  // delta(kq) of the rows this thread reads
  const float win_lo = W_in[w * 64 + n_e * 16 + c0];
  const float win_hi = W_in[w * 64 + n_e * 16 + c0 + 1];
  const float* xr = x + (size_t)(g * 16 + r) * SEQ;
  const unsigned int houtidx = ((unsigned)(g * 16 + r) * RES + w * 64 + n_e * 16 + c0) >> 1;

  const size_t aoff = (size_t)(g * 16 + col) * RES + wave * 128 + kq * 8;

  for (int s = 0; s < SEQ; ++s) {
    float u = xr[s];

    f32x4 acc[4];
#pragma unroll
    for (int n = 0; n < 4; ++n) acc[n] = (f32x4){0.f, 0.f, 0.f, 0.f};

    if (s > 0) {
      const unsigned int tagr = (unsigned)(((s >> 1) + (s & 1)) & 1);
      const f16* Ap = ((s & 1) ? hp1 : hp0) + aoff;   // primary (same-XCD L2)
      const f16* Am = ((s & 1) ? hm1 : hm0) + aoff;   // mirror  (fallback)
      half8 A0, A1, A2, A3;

      // iteration 0: full load from primary
      FULL_LOAD(Ap);
      bool ok = tags_ok(A0, A1, A2, A3, tagr);
      unsigned int it = 0;
      while (!ok) {
        ++it;
        // pace retries (~128cy): laggard waves hit on attempt 1 and never
        // sleep; only ahead-waiting waves pace, cutting redundant 4KB
        // re-fetches through the XCD L2 without adding any serial hop.
        asm volatile("s_sleep 2");
        // verified groups never consult the mirror (never written there);
        // unverified groups take the every-8th-retry LLC fallback (round-6).
        const f16* Pp = (!l2mode && ((it & 7u) == 0u)) ? Am : Ap;
        FULL_LOAD(Pp);
        ok = tags_ok(A0, A1, A2, A3, tagr);
      }

#pragma unroll
      for (int n = 0; n < 4; ++n) acc[n] = __builtin_amdgcn_mfma_f32_16x16x32_f16(A0, Wf[n][0], acc[n], 0, 0, 0);
#pragma unroll
      for (int n = 0; n < 4; ++n) acc[n] = __builtin_amdgcn_mfma_f32_16x16x32_f16(A1, Wf[n][1], acc[n], 0, 0, 0);
#pragma unroll
      for (int n = 0; n < 4; ++n) acc[n] = __builtin_amdgcn_mfma_f32_16x16x32_f16(A2, Wf[n][2], acc[n], 0, 0, 0);
#pragma unroll
      for (int n = 0; n < 4; ++n) acc[n] = __builtin_amdgcn_mfma_f32_16x16x32_f16(A3, Wf[n][3], acc[n], 0, 0, 0);
    }

    // ---- K-split partials to LDS.  D layout: row(batch) = kq*4+j, col = sub-col.
    // delta(kq) column rotation makes this write exact 2-way (see header proof).
#pragma unroll
    for (int n = 0; n < 4; ++n)
#pragma unroll
      for (int j = 0; j < 4; ++j)
        P[PIDX(wave, n, kq * 4 + j, col) + 12 - 4 * kq] = acc[n][j];

    __syncthreads();   // barrier-1: partials complete (full drain; also mops up
                       // the previous step's H-store at zero cost — it has had
                       // the whole load+MFMA phase to complete)

    // ---- reduce over 8 waves (paired reads) + input term + tanh
    float s_lo = 0.f, s_hi = 0.f;
#pragma unroll
    for (int w8 = 0; w8 < 8; ++w8) {
      f32x2 t = *(const f32x2*)&P[PIDX(w8, n_e, r, c0) + rd_off];   // ds_read2_b32
      s_lo += t.x;
      s_hi += t.y;
    }
    float v_lo = fast_tanh(s_lo + u * win_lo);
    float v_hi = fast_tanh(s_hi + u * win_hi);

    const unsigned int tagw = (unsigned)((((s + 1) >> 1) + ((s + 1) & 1)) & 1);
    union { f16 h[2]; unsigned int u32; } pk;
    pk.h[0] = (f16)v_lo;
    pk.h[1] = (f16)v_hi;
    pk.u32  = (pk.u32 & ~1u) | tagw;   // tag in LSB of low fp16 only

    unsigned int* Hp = (unsigned int*)((s & 1) ? hp0 : hp1);
    // primary: plain write-back store -> dirty in local XCD L2 (fast path)
    Hp[houtidx] = pk.u32;
    if (!l2mode) {
      // unverified group: keep the write-through LLC mirror (fallback)
      unsigned int* Hm = (unsigned int*)((s & 1) ? hm0 : hm1);
      __hip_atomic_store(&Hm[houtidx], pk.u32, __ATOMIC_RELAXED,
                         __HIP_MEMORY_SCOPE_AGENT);
    }

    // barrier-2: RAW s_barrier — alignment only, NO vmcnt drain (r16: neutral
    // but harmless; the store commits during the consumer's poll window).
    // Tags make any read-of-in-flight-data a harmless retry. LDS WAR is safe:
    // the reduce's ds_read data was consumed by the tanh/store dataflow above.
    asm volatile("" ::: "memory");         // pin the store before the barrier
    __builtin_amdgcn_s_barrier();
  }
}

// out[b][d] = sum_k h[b][k] * Wout[d][k] + bout[d];  h fp16 from PRIMARY buffer 0
// (H_512, 512 even; kernel-end drain + inter-dispatch writeback publish dirty L2)
__global__ __launch_bounds__(256) void res_readout_kernel(
    const f16* __restrict__ Hf,       // [256][1024] fp16
    const float* __restrict__ Wout,   // [512][1024]
    const float* __restrict__ bout,   // [512]
    float* __restrict__ out)          // [256][512]
{
  __shared__ f16 hs[16][1032];
  __shared__ f16 wsh[32][1032];
  const int tid = threadIdx.x;
  const int bb = blockIdx.x >> 4;   // batch block (16 rows)
  const int db = blockIdx.x & 15;   // d block (32 cols)

  for (int idx = tid; idx < 2048; idx += 256) {
    int row = idx >> 7, cin = idx & 127;
    *(half8*)&hs[row][cin * 8] = *(const half8*)(Hf + (size_t)(bb * 16 + row) * RES + cin * 8);
  }
  for (int idx = tid; idx < 4096; idx += 256) {
    int row = idx >> 7, cin = idx & 127;
    const float* p = Wout + (size_t)(db * 32 + row) * RES + cin * 8;
    f32x4 lo = *(const f32x4*)(p);
    f32x4 hi = *(const f32x4*)(p + 4);
    half8 f;
#pragma unroll
    for (int j = 0; j < 4; ++j) { f[j] = (f16)lo[j]; f[j + 4] = (f16)hi[j]; }
    *(half8*)&wsh[row][cin * 8] = f;
  }
  __syncthreads();

  const int d  = tid & 31;
  const int bp = tid >> 5;
  float acc0 = 0.f, acc1 = 0.f;
  for (int kc = 0; kc < 128; ++kc) {
    half8 wv = *(const half8*)&wsh[d][kc * 8];
    half8 h0 = *(const half8*)&hs[bp * 2][kc * 8];
    half8 h1 = *(const half8*)&hs[bp * 2 + 1][kc * 8];
#pragma unroll
    for (int j = 0; j < 8; ++j) {
      float wf = (float)wv[j];
      acc0 += wf * (float)h0[j];
      acc1 += wf * (float)h1[j];
    }
  }
  float bo = bout[db * 32 + d];
  out[(size_t)(bb * 16 + bp * 2) * 512 + db * 32 + d]     = acc0 + bo;
  out[(size_t)(bb * 16 + bp * 2 + 1) * 512 + db * 32 + d] = acc1 + bo;
}

extern "C" void kernel_launch(void* const* d_in, const int* in_sizes, int n_in,
                              void* d_out, int out_size, void* d_ws, size_t ws_size,
                              hipStream_t stream) {
  (void)in_sizes; (void)n_in; (void)out_size; (void)ws_size;
  const float* x     = (const float*)d_in[0];
  const float* W_in  = (const float*)d_in[1];
  const float* W_res = (const float*)d_in[2];
  const float* Wout  = (const float*)d_in[3];
  const float* bout  = (const float*)d_in[4];
  float* out = (float*)d_out;

  char* ws = (char*)d_ws;
  f16* hp0 = (f16*)(ws);
  f16* hp1 = (f16*)(ws + (512u << 10));
  f16* hm0 = (f16*)(ws + (1024u << 10));
  f16* hm1 = (f16*)(ws + (1536u << 10));
  unsigned int* xcdmap = (unsigned int*)(ws + (2048u << 10));

  // zero all four H buffers (tags: zeros = valid h0 / invalid first-write) and
  // the xcdmap each launch — erases stale state from previous graph replay.
  hipMemsetAsync(ws, 0, (2048u << 10), stream);
  hipMemsetAsync(ws + (2048u << 10), 0, 1024, stream);

  res_recur_kernel<<<dim3(256), dim3(512), 0, stream>>>(x, W_in, W_res,
                                                        hp0, hp1, hm0, hm1, xcdmap);
  res_readout_kernel<<<dim3(256), dim3(256), 0, stream>>>(hp0, Wout, bout, out);
}